// Round 7
// baseline (32.913 us; speedup 1.0000x reference)
//
#include <hip/hip_runtime.h>

#define MARGIN 0.5f
#define NON_MATCH_W 1.0f

__device__ __forceinline__ float4 ld_row_chunk(const float* __restrict__ base,
                                               int b, int row, int k, int N) {
    return reinterpret_cast<const float4*>(base + ((size_t)b * N + row) * 16)[k];
}

// returns sum of squared diffs; h gets the hinge sum for the same chunk
__device__ __forceinline__ float sq_and_hinge(float4 a, float4 c, float& h) {
    const float dx = a.x - c.x, dy = a.y - c.y, dz = a.z - c.z, dw = a.w - c.w;
    const float qx = dx * dx, qy = dy * dy, qz = dz * dz, qw = dw * dw;
    h = fmaxf(0.0f, MARGIN - qx) + fmaxf(0.0f, MARGIN - qy)
      + fmaxf(0.0f, MARGIN - qz) + fmaxf(0.0f, MARGIN - qw);
    return qx + qy + qz + qw;
}

// 8 items per thread. Total items = 4 chunks * 220000 pairs = 880000.
// Thread gid handles items {gid + j*110000, j=0..7}; 110000 % 4 == 0 so the
// chunk index k = gid & 3 is shared by all 8 items. Pair of item j is
// p + j*27500 with p = gid>>2 in [0,27500). Only j=0 can be a match pair
// (matchP = 20000 < 27500); boundary gid = 80000 is a multiple of 64 ->
// wave-uniform branch. Items 1..7 are always nonmatch.
//
// Epilogue: per-block LDS reduce, then 3 device-scope atomicAdds of the
// PRE-SCALED partials directly into out[0..2]. No fence (round-4 lesson:
// __threadfence's L2 writeback per block was the poison, atomics are fine).
// d_out is zeroed by a hipMemsetAsync node before this kernel in the graph.
__global__ __launch_bounds__(256) void cl_main(
    const float* __restrict__ outA, const float* __restrict__ outB,
    const int* __restrict__ matchA, const int* __restrict__ matchB,
    const int* __restrict__ nonMatchA, const int* __restrict__ nonMatchB,
    float* __restrict__ out, int N, int M, int Mn, int B,
    float invM, float invMn)
{
    const int matchP = B * M;                  // 20000
    const int totalP = B * M + B * Mn;         // 220000
    const int PQ = totalP >> 3;                // 27500 pairs per eighth
    const int Q = totalP >> 1;                 // 110000 threads (= totalP*4/8)
    const int gid = blockIdx.x * blockDim.x + threadIdx.x;

    float msum = 0.0f;
    float nsum = 0.0f;

    if (gid < Q) {
        const int k = gid & 3;
        const int p = gid >> 2;                // [0, 27500)

        const bool isM = p < matchP;
        const int flat0 = isM ? p : p - matchP;
        const int* __restrict__ a0arr = isM ? matchA : nonMatchA;
        const int* __restrict__ b0arr = isM ? matchB : nonMatchB;

        // phase 1: all 16 index loads (wave-coalesced; 4 lanes share each int)
        int ia[8], ib[8];
        ia[0] = a0arr[flat0];
        ib[0] = b0arr[flat0];
#pragma unroll
        for (int j = 1; j < 8; ++j) {
            const int fj = p + j * PQ - matchP;    // nonmatch flat index
            ia[j] = nonMatchA[fj];
            ib[j] = nonMatchB[fj];
        }

        int bb[8];
        bb[0] = isM ? (p / M) : (flat0 / Mn);
#pragma unroll
        for (int j = 1; j < 8; ++j) {
            const int fj = p + j * PQ - matchP;
            bb[j] = fj / Mn;
        }

        // phase 2: all 16 row gathers in flight together
        float4 A[8], C[8];
#pragma unroll
        for (int j = 0; j < 8; ++j) {
            A[j] = ld_row_chunk(outA, bb[j], ia[j], k, N);
            C[j] = ld_row_chunk(outB, bb[j], ib[j], k, N);
        }

        // phase 3: math
        float h;
        const float s0 = sq_and_hinge(A[0], C[0], h);
        msum = isM ? s0 : 0.0f;
        nsum = isM ? 0.0f : h;
#pragma unroll
        for (int j = 1; j < 8; ++j) {
            sq_and_hinge(A[j], C[j], h);
            nsum += h;
        }
    }

    // wave-64 reduction
#pragma unroll
    for (int off = 32; off > 0; off >>= 1) {
        msum += __shfl_down(msum, off, 64);
        nsum += __shfl_down(nsum, off, 64);
    }

    __shared__ float sm[4];
    __shared__ float sn[4];
    const int wave = threadIdx.x >> 6;
    if ((threadIdx.x & 63) == 0) {
        sm[wave] = msum;
        sn[wave] = nsum;
    }
    __syncthreads();
    if (threadIdx.x == 0) {
        const float bm = (sm[0] + sm[1] + sm[2] + sm[3]) * invM;
        const float bn = (sn[0] + sn[1] + sn[2] + sn[3]) * (NON_MATCH_W * invMn);
        atomicAdd(&out[0], bm + bn);   // contrastiveLossSum
        atomicAdd(&out[1], bm);        // matchLossSum
        atomicAdd(&out[2], bn);        // nonMatchLossSum
    }
}

extern "C" void kernel_launch(void* const* d_in, const int* in_sizes, int n_in,
                              void* d_out, int out_size, void* d_ws, size_t ws_size,
                              hipStream_t stream) {
    const float* outA = (const float*)d_in[0];
    const float* outB = (const float*)d_in[1];
    const int* matchA = (const int*)d_in[2];
    const int* matchB = (const int*)d_in[3];
    const int* nonMatchA = (const int*)d_in[4];
    const int* nonMatchB = (const int*)d_in[5];
    float* out = (float*)d_out;

    const int B = 4;
    const int D = 16;
    const int N = in_sizes[0] / (B * D);   // 307200
    const int M = in_sizes[2] / B;         // 5000
    const int Mn = in_sizes[4] / B;        // 50000

    const int Q = (B * M + B * Mn) / 2;    // 110000 threads, 8 items each
    const int block = 256;
    const int grid = (Q + block - 1) / block;   // 430

    hipMemsetAsync(d_out, 0, 3 * sizeof(float), stream);
    cl_main<<<grid, block, 0, stream>>>(outA, outB, matchA, matchB,
                                        nonMatchA, nonMatchB, out, N, M, Mn, B,
                                        1.0f / (float)M, 1.0f / (float)Mn);
}

// Round 8
// 17.937 us; speedup vs baseline: 1.8349x; 1.8349x over previous
//
#include <hip/hip_runtime.h>

#define MARGIN 0.5f
#define NON_MATCH_W 1.0f

__device__ __forceinline__ float4 ld_row_chunk(const float* __restrict__ base,
                                               int b, int row, int k, int N) {
    return reinterpret_cast<const float4*>(base + ((size_t)b * N + row) * 16)[k];
}

// returns sum of squared diffs; h gets the hinge sum for the same chunk
__device__ __forceinline__ float sq_and_hinge(float4 a, float4 c, float& h) {
    const float dx = a.x - c.x, dy = a.y - c.y, dz = a.z - c.z, dw = a.w - c.w;
    const float qx = dx * dx, qy = dy * dy, qz = dz * dz, qw = dw * dw;
    h = fmaxf(0.0f, MARGIN - qx) + fmaxf(0.0f, MARGIN - qy)
      + fmaxf(0.0f, MARGIN - qz) + fmaxf(0.0f, MARGIN - qw);
    return qx + qy + qz + qw;
}

// 8 items per thread. Total items = 4 chunks * 220000 pairs = 880000.
// Thread gid handles items {gid + j*110000, j=0..7}; 110000 % 4 == 0 so the
// chunk index k = gid & 3 is shared by all 8 items. Pair of item j is
// p + j*27500 with p = gid>>2 in [0,27500). Only j=0 can be a match pair
// (matchP = 20000 < 27500); boundary gid = 80000 is a multiple of 64 ->
// wave-uniform branch. Items 1..7 are always nonmatch.
__global__ __launch_bounds__(256) void cl_main(
    const float* __restrict__ outA, const float* __restrict__ outB,
    const int* __restrict__ matchA, const int* __restrict__ matchB,
    const int* __restrict__ nonMatchA, const int* __restrict__ nonMatchB,
    float2* __restrict__ partials, int N, int M, int Mn, int B)
{
    const int matchP = B * M;                  // 20000
    const int totalP = B * M + B * Mn;         // 220000
    const int PQ = totalP >> 3;                // 27500 pairs per eighth
    const int Q = totalP >> 1;                 // 110000 threads (= totalP*4/8)
    const int gid = blockIdx.x * blockDim.x + threadIdx.x;

    float msum = 0.0f;
    float nsum = 0.0f;

    if (gid < Q) {
        const int k = gid & 3;
        const int p = gid >> 2;                // [0, 27500)

        const bool isM = p < matchP;
        const int flat0 = isM ? p : p - matchP;
        const int* __restrict__ a0arr = isM ? matchA : nonMatchA;
        const int* __restrict__ b0arr = isM ? matchB : nonMatchB;

        // phase 1: all 16 index loads (wave-coalesced; 4 lanes share each int)
        int ia[8], ib[8];
        ia[0] = a0arr[flat0];
        ib[0] = b0arr[flat0];
#pragma unroll
        for (int j = 1; j < 8; ++j) {
            const int fj = p + j * PQ - matchP;    // nonmatch flat index
            ia[j] = nonMatchA[fj];
            ib[j] = nonMatchB[fj];
        }

        int bb[8];
        bb[0] = isM ? (p / M) : (flat0 / Mn);
#pragma unroll
        for (int j = 1; j < 8; ++j) {
            const int fj = p + j * PQ - matchP;
            bb[j] = fj / Mn;
        }

        // phase 2: all 16 row gathers in flight together
        float4 A[8], C[8];
#pragma unroll
        for (int j = 0; j < 8; ++j) {
            A[j] = ld_row_chunk(outA, bb[j], ia[j], k, N);
            C[j] = ld_row_chunk(outB, bb[j], ib[j], k, N);
        }

        // phase 3: math
        float h;
        const float s0 = sq_and_hinge(A[0], C[0], h);
        msum = isM ? s0 : 0.0f;
        nsum = isM ? 0.0f : h;
#pragma unroll
        for (int j = 1; j < 8; ++j) {
            sq_and_hinge(A[j], C[j], h);
            nsum += h;
        }
    }

    // wave-64 reduction
#pragma unroll
    for (int off = 32; off > 0; off >>= 1) {
        msum += __shfl_down(msum, off, 64);
        nsum += __shfl_down(nsum, off, 64);
    }

    __shared__ float sm[4];
    __shared__ float sn[4];
    const int wave = threadIdx.x >> 6;
    if ((threadIdx.x & 63) == 0) {
        sm[wave] = msum;
        sn[wave] = nsum;
    }
    __syncthreads();
    if (threadIdx.x == 0) {
        partials[blockIdx.x] = make_float2(sm[0] + sm[1] + sm[2] + sm[3],
                                           sn[0] + sn[1] + sn[2] + sn[3]);
    }
}

// Single-wave deterministic reduction of per-block partials -> 3 outputs.
// 64 threads: no LDS, no __syncthreads, just shfl.
__global__ __launch_bounds__(64) void cl_finalize(
    const float2* __restrict__ partials, float* __restrict__ out,
    int nblocks, float invM, float invMn)
{
    float msum = 0.0f;
    float nsum = 0.0f;
    for (int i = threadIdx.x; i < nblocks; i += 64) {
        const float2 v = partials[i];
        msum += v.x;
        nsum += v.y;
    }
#pragma unroll
    for (int off = 32; off > 0; off >>= 1) {
        msum += __shfl_down(msum, off, 64);
        nsum += __shfl_down(nsum, off, 64);
    }
    if (threadIdx.x == 0) {
        const float m = msum * invM;
        const float n = nsum * NON_MATCH_W * invMn;
        out[0] = m + n;
        out[1] = m;
        out[2] = n;
    }
}

extern "C" void kernel_launch(void* const* d_in, const int* in_sizes, int n_in,
                              void* d_out, int out_size, void* d_ws, size_t ws_size,
                              hipStream_t stream) {
    const float* outA = (const float*)d_in[0];
    const float* outB = (const float*)d_in[1];
    const int* matchA = (const int*)d_in[2];
    const int* matchB = (const int*)d_in[3];
    const int* nonMatchA = (const int*)d_in[4];
    const int* nonMatchB = (const int*)d_in[5];
    float* out = (float*)d_out;
    float2* partials = (float2*)d_ws;

    const int B = 4;
    const int D = 16;
    const int N = in_sizes[0] / (B * D);   // 307200
    const int M = in_sizes[2] / B;         // 5000
    const int Mn = in_sizes[4] / B;        // 50000

    const int Q = (B * M + B * Mn) / 2;    // 110000 threads, 8 items each
    const int block = 256;
    const int grid = (Q + block - 1) / block;   // 430

    cl_main<<<grid, block, 0, stream>>>(outA, outB, matchA, matchB,
                                        nonMatchA, nonMatchB, partials, N, M, Mn, B);
    cl_finalize<<<1, 64, 0, stream>>>(partials, out, grid,
                                      1.0f / (float)M, 1.0f / (float)Mn);
}

// Round 9
// 17.174 us; speedup vs baseline: 1.9164x; 1.0444x over previous
//
#include <hip/hip_runtime.h>

#define MARGIN 0.5f
#define NON_MATCH_W 1.0f

__device__ __forceinline__ float4 ld_row_chunk(const float* __restrict__ base,
                                               int b, int row, int k, int N) {
    return reinterpret_cast<const float4*>(base + ((size_t)b * N + row) * 16)[k];
}

// returns sum of squared diffs; h gets the hinge sum for the same chunk
__device__ __forceinline__ float sq_and_hinge(float4 a, float4 c, float& h) {
    const float dx = a.x - c.x, dy = a.y - c.y, dz = a.z - c.z, dw = a.w - c.w;
    const float qx = dx * dx, qy = dy * dy, qz = dz * dz, qw = dw * dw;
    h = fmaxf(0.0f, MARGIN - qx) + fmaxf(0.0f, MARGIN - qy)
      + fmaxf(0.0f, MARGIN - qz) + fmaxf(0.0f, MARGIN - qw);
    return qx + qy + qz + qw;
}

// 8 items per thread. Total items = 4 chunks * 220000 pairs = 880000.
// Thread gid handles items {gid + j*110000, j=0..7}; 110000 % 4 == 0 so the
// chunk index k = gid & 3 is shared by all 8 items. Pair of item j is
// p + j*27500 with p = gid>>2 in [0,27500). Only j=0 can be a match pair
// (matchP = 20000 < 27500); boundary gid = 80000 is a multiple of 64 ->
// wave-uniform branch. Items 1..7 are always nonmatch.
__global__ __launch_bounds__(256) void cl_main(
    const float* __restrict__ outA, const float* __restrict__ outB,
    const int* __restrict__ matchA, const int* __restrict__ matchB,
    const int* __restrict__ nonMatchA, const int* __restrict__ nonMatchB,
    float* __restrict__ partials, int N, int M, int Mn, int B)
{
    const int matchP = B * M;                  // 20000
    const int totalP = B * M + B * Mn;         // 220000
    const int PQ = totalP >> 3;                // 27500 pairs per eighth
    const int Q = totalP >> 1;                 // 110000 threads (= totalP*4/8)
    const int gid = blockIdx.x * blockDim.x + threadIdx.x;

    float msum = 0.0f;
    float nsum = 0.0f;

    if (gid < Q) {
        const int k = gid & 3;
        const int p = gid >> 2;                // [0, 27500)

        const bool isM = p < matchP;
        const int flat0 = isM ? p : p - matchP;
        const int* __restrict__ a0arr = isM ? matchA : nonMatchA;
        const int* __restrict__ b0arr = isM ? matchB : nonMatchB;

        // phase 1: all 16 index loads (wave-coalesced; 4 lanes share each int)
        int ia[8], ib[8];
        ia[0] = a0arr[flat0];
        ib[0] = b0arr[flat0];
#pragma unroll
        for (int j = 1; j < 8; ++j) {
            const int fj = p + j * PQ - matchP;    // nonmatch flat index
            ia[j] = nonMatchA[fj];
            ib[j] = nonMatchB[fj];
        }

        int bb[8];
        bb[0] = isM ? (p / M) : (flat0 / Mn);
#pragma unroll
        for (int j = 1; j < 8; ++j) {
            const int fj = p + j * PQ - matchP;
            bb[j] = fj / Mn;
        }

        // phase 2: all 16 row gathers in flight together
        float4 A[8], C[8];
#pragma unroll
        for (int j = 0; j < 8; ++j) {
            A[j] = ld_row_chunk(outA, bb[j], ia[j], k, N);
            C[j] = ld_row_chunk(outB, bb[j], ib[j], k, N);
        }

        // phase 3: math
        float h;
        const float s0 = sq_and_hinge(A[0], C[0], h);
        msum = isM ? s0 : 0.0f;
        nsum = isM ? 0.0f : h;
#pragma unroll
        for (int j = 1; j < 8; ++j) {
            sq_and_hinge(A[j], C[j], h);
            nsum += h;
        }
    }

    // wave-64 reduction
#pragma unroll
    for (int off = 32; off > 0; off >>= 1) {
        msum += __shfl_down(msum, off, 64);
        nsum += __shfl_down(nsum, off, 64);
    }

    __shared__ float sm[4];
    __shared__ float sn[4];
    const int wave = threadIdx.x >> 6;
    if ((threadIdx.x & 63) == 0) {
        sm[wave] = msum;
        sn[wave] = nsum;
    }
    __syncthreads();
    if (threadIdx.x == 0) {
        partials[2 * blockIdx.x]     = sm[0] + sm[1] + sm[2] + sm[3];
        partials[2 * blockIdx.x + 1] = sn[0] + sn[1] + sn[2] + sn[3];
    }
}

// Single-block deterministic reduction of per-block partials -> 3 outputs.
__global__ __launch_bounds__(256) void cl_finalize(
    const float* __restrict__ partials, float* __restrict__ out,
    int nblocks, float invM, float invMn)
{
    float msum = 0.0f;
    float nsum = 0.0f;
    const float2* p2 = reinterpret_cast<const float2*>(partials);
    for (int i = threadIdx.x; i < nblocks; i += 256) {
        const float2 v = p2[i];
        msum += v.x;
        nsum += v.y;
    }
#pragma unroll
    for (int off = 32; off > 0; off >>= 1) {
        msum += __shfl_down(msum, off, 64);
        nsum += __shfl_down(nsum, off, 64);
    }
    __shared__ float sm[4];
    __shared__ float sn[4];
    const int wave = threadIdx.x >> 6;
    if ((threadIdx.x & 63) == 0) {
        sm[wave] = msum;
        sn[wave] = nsum;
    }
    __syncthreads();
    if (threadIdx.x == 0) {
        const float m = (sm[0] + sm[1] + sm[2] + sm[3]) * invM;
        const float n = (sn[0] + sn[1] + sn[2] + sn[3]) * NON_MATCH_W * invMn;
        out[0] = m + n;
        out[1] = m;
        out[2] = n;
    }
}

extern "C" void kernel_launch(void* const* d_in, const int* in_sizes, int n_in,
                              void* d_out, int out_size, void* d_ws, size_t ws_size,
                              hipStream_t stream) {
    const float* outA = (const float*)d_in[0];
    const float* outB = (const float*)d_in[1];
    const int* matchA = (const int*)d_in[2];
    const int* matchB = (const int*)d_in[3];
    const int* nonMatchA = (const int*)d_in[4];
    const int* nonMatchB = (const int*)d_in[5];
    float* out = (float*)d_out;
    float* partials = (float*)d_ws;

    const int B = 4;
    const int D = 16;
    const int N = in_sizes[0] / (B * D);   // 307200
    const int M = in_sizes[2] / B;         // 5000
    const int Mn = in_sizes[4] / B;        // 50000

    const int Q = (B * M + B * Mn) / 2;    // 110000 threads, 8 items each
    const int block = 256;
    const int grid = (Q + block - 1) / block;   // 430

    cl_main<<<grid, block, 0, stream>>>(outA, outB, matchA, matchB,
                                        nonMatchA, nonMatchB, partials, N, M, Mn, B);
    cl_finalize<<<1, block, 0, stream>>>(partials, out, grid,
                                         1.0f / (float)M, 1.0f / (float)Mn);
}